// Round 1
// baseline (872.956 us; speedup 1.0000x reference)
//
#include <hip/hip_runtime.h>
#include <cstdint>
#include <cstddef>

// Problem constants (fixed shapes from setup_inputs)
#define Tt 4096      // tokens = B*S
#define Hd 2048      // hidden
#define Fd 2048      // ffn
#define En 8         // experts
#define Rcap 9216    // 8192 assignments + 8*128 padding

typedef short bf16x8 __attribute__((ext_vector_type(8)));
typedef float f32x4 __attribute__((ext_vector_type(4)));
typedef unsigned int u32;
typedef u32 __attribute__((address_space(1))) gas_u32;
typedef u32 __attribute__((address_space(3))) las_u32;

__device__ __forceinline__ unsigned short f2bf(float f) {
    u32 u = __builtin_bit_cast(u32, f);
    u = (u + 0x7FFFu + ((u >> 16) & 1u)) >> 16;   // round-to-nearest-even
    return (unsigned short)u;
}
__device__ __forceinline__ float bf2f(unsigned short s) {
    return __builtin_bit_cast(float, ((u32)s) << 16);
}

// ---------------- Router: fp32 logits, softmax, top-2, renormalize ----------
__global__ __launch_bounds__(256) void router_kernel(
    const float* __restrict__ x, const float* __restrict__ gate,
    int* __restrict__ topi, float* __restrict__ topw)
{
    const int t = blockIdx.x;
    const float* xr = x + (size_t)t * Hd;
    float acc[En];
    #pragma unroll
    for (int e = 0; e < En; ++e) acc[e] = 0.f;
    for (int h = threadIdx.x; h < Hd; h += 256) {
        const float xv = xr[h];
        #pragma unroll
        for (int e = 0; e < En; ++e) acc[e] += xv * gate[e * Hd + h];
    }
    #pragma unroll
    for (int e = 0; e < En; ++e) {
        float v = acc[e];
        for (int d = 32; d > 0; d >>= 1) v += __shfl_down(v, d, 64);
        acc[e] = v;
    }
    __shared__ float red[En][4];
    const int lane = threadIdx.x & 63, wv = threadIdx.x >> 6;
    if (lane == 0) {
        #pragma unroll
        for (int e = 0; e < En; ++e) red[e][wv] = acc[e];
    }
    __syncthreads();
    if (threadIdx.x == 0) {
        float l[En];
        #pragma unroll
        for (int e = 0; e < En; ++e) l[e] = red[e][0] + red[e][1] + red[e][2] + red[e][3];
        float m = l[0];
        #pragma unroll
        for (int e = 1; e < En; ++e) m = fmaxf(m, l[e]);
        float p[En];
        #pragma unroll
        for (int e = 0; e < En; ++e) p[e] = expf(l[e] - m);
        int i1 = 0;
        #pragma unroll
        for (int e = 1; e < En; ++e) if (p[e] > p[i1]) i1 = e;
        int i2 = (i1 == 0) ? 1 : 0;
        #pragma unroll
        for (int e = 0; e < En; ++e) if (e != i1 && p[e] > p[i2]) i2 = e;
        const float s = p[i1] + p[i2];
        topi[2 * t] = i1; topi[2 * t + 1] = i2;
        topw[2 * t] = p[i1] / s; topw[2 * t + 1] = p[i2] / s;
    }
}

// ---------------- Expert assignment ----------------------------------------
__global__ void assign_kernel(const int* __restrict__ topi, int* __restrict__ cnt,
                              int* __restrict__ posbuf)
{
    const int idx = blockIdx.x * blockDim.x + threadIdx.x;
    if (idx >= Tt * 2) return;
    posbuf[idx] = atomicAdd(&cnt[topi[idx]], 1);
}

__global__ void scan_kernel(const int* __restrict__ cnt, int* __restrict__ off,
                            int* __restrict__ pcnt)
{
    if (threadIdx.x == 0 && blockIdx.x == 0) {
        int a = 0;
        for (int e = 0; e < En; ++e) {
            off[e] = a;
            const int pc = (cnt[e] + 127) & ~127;
            pcnt[e] = pc;
            a += pc;
        }
    }
}

// Gather x rows -> bf16 Xg (permuted by expert); record token/weight per row.
__global__ __launch_bounds__(256) void gather_kernel(
    const float* __restrict__ x, const int* __restrict__ topi,
    const float* __restrict__ topw, const int* __restrict__ off,
    const int* __restrict__ posbuf, unsigned short* __restrict__ Xg,
    int* __restrict__ tokrow, float* __restrict__ wrow)
{
    const int entry = blockIdx.x;           // 0..8191
    const int t = entry >> 1;
    const int e = topi[entry];
    const int row = off[e] + posbuf[entry];
    if (threadIdx.x == 0) { tokrow[row] = t; wrow[row] = topw[entry]; }
    const float4* src = (const float4*)(x + (size_t)t * Hd);
    const int i = threadIdx.x;              // 8 elems per thread
    const float4 a = src[2 * i], b = src[2 * i + 1];
    unsigned short o[8];
    o[0] = f2bf(a.x); o[1] = f2bf(a.y); o[2] = f2bf(a.z); o[3] = f2bf(a.w);
    o[4] = f2bf(b.x); o[5] = f2bf(b.y); o[6] = f2bf(b.z); o[7] = f2bf(b.w);
    ((uint4*)(Xg + (size_t)row * Hd))[i] = *(const uint4*)o;
}

// ---------------- Weight transpose + bf16 convert: [E][K][N] -> [E][N][K] ---
__global__ __launch_bounds__(256) void transpose_kernel(
    const float* __restrict__ w1s, const float* __restrict__ w3s,
    const float* __restrict__ w2s, unsigned short* __restrict__ w1T,
    unsigned short* __restrict__ w3T, unsigned short* __restrict__ w2T)
{
    __shared__ float tile[32][33];
    const int z = blockIdx.z, tensor = z >> 3, e = z & 7;
    const float* src = (tensor == 0) ? w1s : (tensor == 1) ? w3s : w2s;
    unsigned short* dst = (tensor == 0) ? w1T : (tensor == 1) ? w3T : w2T;
    const int c0 = blockIdx.x * 32, r0 = blockIdx.y * 32;
    const int tx = threadIdx.x & 31, ty = threadIdx.x >> 5;
    const size_t base = (size_t)e * 2048 * 2048;
    #pragma unroll
    for (int r = 0; r < 4; ++r)
        tile[ty + r * 8][tx] = src[base + (size_t)(r0 + ty + r * 8) * 2048 + c0 + tx];
    __syncthreads();
    #pragma unroll
    for (int r = 0; r < 4; ++r)
        dst[base + (size_t)(c0 + ty + r * 8) * 2048 + r0 + tx] = f2bf(tile[tx][ty + r * 8]);
}

// ---------------- GEMM: C[M,N] = A[M,K] * B[N,K]^T  (both K-major, bf16) ----
// m97 structure: 128x128 tile, BK=64, global_load_lds width 16, XOR-swizzled
// LDS chunk layout so ds_read_b128 fragment loads are bank-conflict-free.
// EPI==0: dual output (h1 into C0 for even z, h3 into C1 for odd z), bf16.
// EPI==1: scatter out += wrow[row] * val via fp32 HW atomics.
template <int EPI>
__global__ __launch_bounds__(256) void gemm_kernel(
    const unsigned short* __restrict__ Ab,
    const unsigned short* __restrict__ Bb0,
    const unsigned short* __restrict__ Bb1,
    unsigned short* __restrict__ C0,
    unsigned short* __restrict__ C1,
    float* __restrict__ outp,
    const int* __restrict__ off, const int* __restrict__ pcnt,
    const int* __restrict__ tokrow, const float* __restrict__ wrow)
{
    const int z = blockIdx.z;
    const int e = (EPI == 0) ? (z >> 1) : z;
    const int mt = blockIdx.y;
    const int pc = pcnt[e];
    if (mt * 128 >= pc) return;            // expert has fewer padded rows
    const int nt = blockIdx.x;
    const int row0 = off[e] + mt * 128;

    const unsigned short* A = Ab + (size_t)row0 * 2048;
    const unsigned short* Bsel = (EPI == 0 && (z & 1)) ? Bb1 : Bb0;
    const unsigned short* B = Bsel + (size_t)e * 2048 * 2048 + (size_t)nt * 128 * 2048;

    __shared__ __align__(16) unsigned short As[128 * 64];
    __shared__ __align__(16) unsigned short Bs[128 * 64];

    const int tid = threadIdx.x;
    const int lane = tid & 63;
    const int wv = tid >> 6;
    const int wm = wv & 1, wn = wv >> 1;
    const int quad = lane >> 4, l16 = lane & 15;

    f32x4 acc[4][4];
    const f32x4 zero4 = {0.f, 0.f, 0.f, 0.f};
    #pragma unroll
    for (int i = 0; i < 4; ++i)
        #pragma unroll
        for (int j = 0; j < 4; ++j) acc[i][j] = zero4;

    for (int kt = 0; kt < 2048; kt += 64) {
        __syncthreads();
        #pragma unroll
        for (int i = 0; i < 4; ++i) {
            const int grp = i * 4 + wv;
            const int idx = grp * 64 + lane;
            const int r = idx >> 3;
            const int kc = (idx & 7) ^ (r & 7);     // XOR swizzle of 16B chunks
            const unsigned short* ga = A + (size_t)r * 2048 + kt + kc * 8;
            __builtin_amdgcn_global_load_lds((const gas_u32*)ga,
                                             (las_u32*)(As + grp * 512), 16, 0, 0);
            const unsigned short* gb = B + (size_t)r * 2048 + kt + kc * 8;
            __builtin_amdgcn_global_load_lds((const gas_u32*)gb,
                                             (las_u32*)(Bs + grp * 512), 16, 0, 0);
        }
        __syncthreads();
        #pragma unroll
        for (int ks = 0; ks < 2; ++ks) {
            bf16x8 af[4], bfr[4];
            #pragma unroll
            for (int mi = 0; mi < 4; ++mi) {
                const int m = wm * 64 + mi * 16 + l16;
                const int ck = ks * 4 + quad;
                const int slot = m * 8 + (ck ^ (m & 7));
                af[mi] = *(const bf16x8*)(As + slot * 8);
            }
            #pragma unroll
            for (int ni = 0; ni < 4; ++ni) {
                const int n = wn * 64 + ni * 16 + l16;
                const int ck = ks * 4 + quad;
                const int slot = n * 8 + (ck ^ (n & 7));
                bfr[ni] = *(const bf16x8*)(Bs + slot * 8);
            }
            #pragma unroll
            for (int mi = 0; mi < 4; ++mi)
                #pragma unroll
                for (int ni = 0; ni < 4; ++ni)
                    acc[mi][ni] = __builtin_amdgcn_mfma_f32_16x16x32_bf16(
                        af[mi], bfr[ni], acc[mi][ni], 0, 0, 0);
        }
    }

    if (EPI == 0) {
        unsigned short* C = (z & 1) ? C1 : C0;
        #pragma unroll
        for (int mi = 0; mi < 4; ++mi) {
            const int rbase = row0 + wm * 64 + mi * 16 + quad * 4;
            #pragma unroll
            for (int ni = 0; ni < 4; ++ni) {
                const int col = nt * 128 + wn * 64 + ni * 16 + l16;
                #pragma unroll
                for (int r = 0; r < 4; ++r)
                    C[(size_t)(rbase + r) * 2048 + col] = f2bf(acc[mi][ni][r]);
            }
        }
    } else {
        #pragma unroll
        for (int mi = 0; mi < 4; ++mi) {
            const int rbase = row0 + wm * 64 + mi * 16 + quad * 4;
            #pragma unroll
            for (int r = 0; r < 4; ++r) {
                const int rg = rbase + r;
                const int t = tokrow[rg];
                const float w = wrow[rg];           // 0.0 on pad rows
                float* orow = outp + (size_t)t * 2048 + nt * 128 + wn * 64;
                #pragma unroll
                for (int ni = 0; ni < 4; ++ni)
                    unsafeAtomicAdd(orow + ni * 16 + l16, acc[mi][ni][r] * w);
            }
        }
    }
}

// ---------------- G = silu(h1) * h3 (in place into H1 buffer) --------------
__global__ __launch_bounds__(256) void silumul_kernel(
    unsigned short* __restrict__ H1buf, const unsigned short* __restrict__ H3buf)
{
    const size_t idx = ((size_t)blockIdx.x * 256 + threadIdx.x) * 8;
    uint4 h1 = *(const uint4*)(H1buf + idx);
    const uint4 h3 = *(const uint4*)(H3buf + idx);
    unsigned short* p1 = (unsigned short*)&h1;
    const unsigned short* p3 = (const unsigned short*)&h3;
    #pragma unroll
    for (int j = 0; j < 8; ++j) {
        const float a = bf2f(p1[j]);
        const float b = bf2f(p3[j]);
        const float s = a / (1.f + expf(-a));
        p1[j] = f2bf(s * b);
    }
    *(uint4*)(H1buf + idx) = h1;
}

// ---------------- Workspace layout ------------------------------------------
static constexpr size_t SZ_WT  = (size_t)En * 2048 * 2048 * 2;  // 64 MiB each
static constexpr size_t SZ_XG  = (size_t)Rcap * 2048 * 2;       // 36 MiB each
static constexpr size_t O_W1T  = 0;
static constexpr size_t O_W3T  = O_W1T + SZ_WT;
static constexpr size_t O_W2T  = O_W3T + SZ_WT;
static constexpr size_t O_XG   = O_W2T + SZ_WT;
static constexpr size_t O_H1   = O_XG + SZ_XG;
static constexpr size_t O_H3   = O_H1 + SZ_XG;
static constexpr size_t O_TOPI = O_H3 + SZ_XG;
static constexpr size_t O_TOPW = O_TOPI + (size_t)Tt * 2 * 4;
static constexpr size_t O_POS  = O_TOPW + (size_t)Tt * 2 * 4;
static constexpr size_t O_OFF  = O_POS + (size_t)Tt * 2 * 4;
static constexpr size_t O_PCNT = O_OFF + 64;
static constexpr size_t O_CNT  = O_PCNT + 64;          // ---- zeroed region ----
static constexpr size_t O_TOKROW = O_CNT + 64;
static constexpr size_t O_WROW = O_TOKROW + (size_t)Rcap * 4;
static constexpr size_t ZERO_SZ = 64 + (size_t)Rcap * 4 + (size_t)Rcap * 4;

extern "C" void kernel_launch(void* const* d_in, const int* in_sizes, int n_in,
                              void* d_out, int out_size, void* d_ws, size_t ws_size,
                              hipStream_t stream)
{
    const float* x    = (const float*)d_in[0];
    const float* gate = (const float*)d_in[1];
    const float* w1s  = (const float*)d_in[2];
    const float* w2s  = (const float*)d_in[3];
    const float* w3s  = (const float*)d_in[4];
    float* out = (float*)d_out;
    char* ws = (char*)d_ws;

    unsigned short* w1T = (unsigned short*)(ws + O_W1T);
    unsigned short* w3T = (unsigned short*)(ws + O_W3T);
    unsigned short* w2T = (unsigned short*)(ws + O_W2T);
    unsigned short* Xg  = (unsigned short*)(ws + O_XG);
    unsigned short* H1  = (unsigned short*)(ws + O_H1);
    unsigned short* H3  = (unsigned short*)(ws + O_H3);
    int*   topi   = (int*)(ws + O_TOPI);
    float* topw   = (float*)(ws + O_TOPW);
    int*   posbuf = (int*)(ws + O_POS);
    int*   off    = (int*)(ws + O_OFF);
    int*   pcnt   = (int*)(ws + O_PCNT);
    int*   cnt    = (int*)(ws + O_CNT);
    int*   tokrow = (int*)(ws + O_TOKROW);
    float* wrow   = (float*)(ws + O_WROW);

    hipMemsetAsync(out, 0, (size_t)Tt * Hd * 4, stream);
    hipMemsetAsync(ws + O_XG, 0, SZ_XG, stream);           // pad rows read as 0
    hipMemsetAsync(ws + O_CNT, 0, ZERO_SZ, stream);        // cnt + tokrow + wrow

    transpose_kernel<<<dim3(64, 64, 24), 256, 0, stream>>>(w1s, w3s, w2s, w1T, w3T, w2T);
    router_kernel<<<Tt, 256, 0, stream>>>(x, gate, topi, topw);
    assign_kernel<<<(Tt * 2) / 256, 256, 0, stream>>>(topi, cnt, posbuf);
    scan_kernel<<<1, 64, 0, stream>>>(cnt, off, pcnt);
    gather_kernel<<<Tt * 2, 256, 0, stream>>>(x, topi, topw, off, posbuf, Xg, tokrow, wrow);

    // h1 = Xg*W1^T, h3 = Xg*W3^T (z even/odd picks W1/W3)
    gemm_kernel<0><<<dim3(16, 32, 16), 256, 0, stream>>>(
        Xg, w1T, w3T, H1, H3, nullptr, off, pcnt, tokrow, wrow);
    // G = silu(h1)*h3, in place into H1
    silumul_kernel<<<(Rcap * Fd) / 2048, 256, 0, stream>>>(H1, H3);
    // out[t] += w * (G * W2^T)
    gemm_kernel<1><<<dim3(16, 32, 8), 256, 0, stream>>>(
        H1, w2T, nullptr, nullptr, nullptr, out, off, pcnt, tokrow, wrow);
}